// Round 20
// baseline (273.948 us; speedup 1.0000x reference)
//
#include <hip/hip_runtime.h>

#define B_ 8
#define N_ 1024
#define D_ 768
#define H_ 12
#define HD 64
#define M_ (B_*N_)

typedef short short8 __attribute__((ext_vector_type(8)));
typedef float f32x4 __attribute__((ext_vector_type(4)));
typedef float f32x16 __attribute__((ext_vector_type(16)));
typedef int int4v __attribute__((ext_vector_type(4)));

__device__ __forceinline__ unsigned short f2bf(float f) {
    union { float f; unsigned int u; } c; c.f = f;
    unsigned int u = c.u;
    unsigned int r = (u + 0x7fffu + ((u >> 16) & 1u)) >> 16;
    return (unsigned short)r;
}

__device__ __forceinline__ float exp2_hw(float x) {
    float r;
    asm("v_exp_f32 %0, %1" : "=v"(r) : "v"(x));
    return r;
}

__device__ __forceinline__ unsigned int cvtpk_bf16(float a, float b) {
    unsigned int r;
    asm("v_cvt_pk_bf16_f32 %0, %1, %2" : "=v"(r) : "v"(a), "v"(b));
    return r;
}

// swap a's lanes32-63 with b's lanes0-31. "+&v" early-clobber forces distinct
// VGPRs (plain "+v" lets the allocator coalesce equal-valued operands — r5 bug).
#define PLSWAP(a, b) asm volatile("v_permlane32_swap_b32 %0, %1" : "+&v"(a), "+&v"(b))

__device__ __forceinline__ short8 pack4(unsigned int a, unsigned int b,
                                        unsigned int c, unsigned int d) {
    union { int4v i; short8 s; } u;
    u.i = (int4v){(int)a, (int)b, (int)c, (int)d};
    return u.s;
}

__device__ __forceinline__ void gload16(const void* g, void* l) {
    __builtin_amdgcn_global_load_lds(
        (const __attribute__((address_space(1))) unsigned int*)g,
        (__attribute__((address_space(3))) unsigned int*)l, 16, 0, 0);
}

// ---------------- fused prep: cast x (32B/thread); LDS-tiled W transpose ----

__global__ __launch_bounds__(256) void prep_kernel(
    const float* __restrict__ x, const float* __restrict__ wqkv,
    const float* __restrict__ wproj,
    unsigned short* __restrict__ xb, unsigned short* __restrict__ wqkvT,
    unsigned short* __restrict__ wprojT)
{
    int bid = blockIdx.x, tid = threadIdx.x;
    if (bid < 3072) {
        int i = (bid * 256 + tid) * 2;
        float4 v0 = reinterpret_cast<const float4*>(x)[i];
        float4 v1 = reinterpret_cast<const float4*>(x)[i + 1];
        ushort4 o0, o1;
        o0.x = f2bf(v0.x); o0.y = f2bf(v0.y); o0.z = f2bf(v0.z); o0.w = f2bf(v0.w);
        o1.x = f2bf(v1.x); o1.y = f2bf(v1.y); o1.z = f2bf(v1.z); o1.w = f2bf(v1.w);
        reinterpret_cast<ushort4*>(xb)[i] = o0;
        reinterpret_cast<ushort4*>(xb)[i + 1] = o1;
        return;
    }
    __shared__ unsigned short T[64][72];
    const float* W; unsigned short* wT; int Rr, Cc, idx;
    if (bid < 3072 + 432) { W = wqkv;  wT = wqkvT;  Rr = 768; Cc = 2304; idx = bid - 3072; }
    else                  { W = wproj; wT = wprojT; Rr = 768; Cc = 768;  idx = bid - 3504; }
    int ntc = Cc >> 6;
    int tc = idx % ntc, tr = idx / ntc;
    int r0 = tr * 64, c0 = tc * 64;
    {
        int row = tid >> 2, cg = (tid & 3) * 16;
        const float4* src = reinterpret_cast<const float4*>(&W[(size_t)(r0 + row) * Cc + c0 + cg]);
        ushort4 o[4];
        #pragma unroll
        for (int j = 0; j < 4; j++) {
            float4 v = src[j];
            o[j].x = f2bf(v.x); o[j].y = f2bf(v.y); o[j].z = f2bf(v.z); o[j].w = f2bf(v.w);
        }
        #pragma unroll
        for (int j = 0; j < 4; j++)
            *reinterpret_cast<ushort4*>(&T[row][cg + j * 4]) = o[j];
    }
    __syncthreads();
    {
        int orow = tid >> 2, rg = (tid & 3) * 16;
        unsigned short tmp[16];
        #pragma unroll
        for (int j = 0; j < 16; j++) tmp[j] = T[rg + j][orow];
        uint4* dst = reinterpret_cast<uint4*>(&wT[(size_t)(c0 + orow) * Rr + r0 + rg]);
        dst[0] = *reinterpret_cast<const uint4*>(&tmp[0]);
        dst[1] = *reinterpret_cast<const uint4*>(&tmp[8]);
    }
}

// ---------------- gemm<0>: 256x128, 8 waves, BK=32, DEPTH-2, PHASE-SPLIT ----
// r20: occupancy-tail fix. Depth-3 (72 KB) capped at 2 blocks/CU -> grid 576
// vs 512 slots -> 64-block straggler wave (~12.5% wall). Depth-2 = 48 KB ->
// 3 blocks/CU -> all 576 co-resident. Cost: end-of-tile vmcnt(0) drain, but
// loads are L2-hits (XCD chunking) issued a full phase-split tile (~600-800cy)
// ahead, and the 3rd block/CU adds TLP. Phase-split + setprio + sched_barrier
// discipline unchanged (r16-proven).

__global__ __launch_bounds__(512, 6) void gemm0_kernel(
    const unsigned short* __restrict__ A,
    const unsigned short* __restrict__ Bt,
    const float* __restrict__ bias,
    unsigned short* __restrict__ qo,
    unsigned short* __restrict__ ko,
    unsigned short* __restrict__ vo)
{
    const int K = D_;                       // 768
    const int KT = K >> 5;                  // 24
    __shared__ alignas(16) unsigned short As[2 * 8192];   // 32 KB
    __shared__ alignas(16) unsigned short Bs[2 * 4096];   // 16 KB

    int tid = threadIdx.x;
    int lane = tid & 63, w = tid >> 6;
    int wr = w >> 1, wc = w & 1;

    int m0 = blockIdx.y * 256, n0 = blockIdx.x * 128;

    int lr = lane & 15;
    int kc = lane >> 4;
    int org = (lane >> 4) * 4;

    int srA = w * 16 + (lane >> 2);
    int scA0 = (lane & 3) ^ (srA & 3);
    int srA1 = 128 + srA;
    int scA1 = (lane & 3) ^ (srA1 & 3);
    const unsigned short* gA0 = A + (size_t)(m0 + srA) * K + scA0 * 8;
    const unsigned short* gA1 = A + (size_t)(m0 + srA1) * K + scA1 * 8;
    const unsigned short* gB0 = Bt + (size_t)(n0 + srA) * K + scA0 * 8;

    f32x4 acc[4][4] = {};

#define STAGE_A(buf, k0)                                                   \
    do {                                                                   \
        gload16(gA0 + (k0), As + (buf) * 8192 + w * 512);                  \
        gload16(gA1 + (k0), As + (buf) * 8192 + 4096 + w * 512);           \
    } while (0)
#define STAGE_B(buf, k0) gload16(gB0 + (k0), Bs + (buf) * 4096 + w * 512)

    STAGE_A(0, 0); STAGE_B(0, 0);
    asm volatile("s_waitcnt vmcnt(0)" ::: "memory");
    __builtin_amdgcn_s_barrier();
    __builtin_amdgcn_sched_barrier(0);

    int cur = 0;
    for (int kt = 0; kt < KT; ++kt) {
        int sb = cur ^ 1;
        bool pf = (kt + 1 < KT);
        const unsigned short* Ab = As + cur * 8192;
        const unsigned short* Bb = Bs + cur * 4096;

        // ---- phase 0: A-frags m0,m1 + all B-frags; stage A of kt+1 ----
        short8 af0, af1, bf[4];
        {
            int r0 = wr * 64 + lr;
            int r1 = wr * 64 + 16 + lr;
            af0 = *reinterpret_cast<const short8*>(&Ab[r0 * 32 + (kc ^ (r0 & 3)) * 8]);
            af1 = *reinterpret_cast<const short8*>(&Ab[r1 * 32 + (kc ^ (r1 & 3)) * 8]);
            #pragma unroll
            for (int ni = 0; ni < 4; ni++) {
                int rb = wc * 64 + ni * 16 + lr;
                bf[ni] = *reinterpret_cast<const short8*>(&Bb[rb * 32 + (kc ^ (rb & 3)) * 8]);
            }
        }
        if (pf) STAGE_A(sb, (kt + 1) * 32);
        __builtin_amdgcn_s_barrier();
        asm volatile("s_waitcnt lgkmcnt(0)" ::: "memory");
        __builtin_amdgcn_sched_barrier(0);
        __builtin_amdgcn_s_setprio(1);
        #pragma unroll
        for (int ni = 0; ni < 4; ni++) {
            acc[0][ni] = __builtin_amdgcn_mfma_f32_16x16x32_bf16(af0, bf[ni], acc[0][ni], 0, 0, 0);
            acc[1][ni] = __builtin_amdgcn_mfma_f32_16x16x32_bf16(af1, bf[ni], acc[1][ni], 0, 0, 0);
        }
        __builtin_amdgcn_s_setprio(0);
        __builtin_amdgcn_s_barrier();
        __builtin_amdgcn_sched_barrier(0);

        // ---- phase 1: A-frags m2,m3; stage B of kt+1; end-of-tile drain ----
        short8 af2, af3;
        {
            int r2 = wr * 64 + 32 + lr;
            int r3 = wr * 64 + 48 + lr;
            af2 = *reinterpret_cast<const short8*>(&Ab[r2 * 32 + (kc ^ (r2 & 3)) * 8]);
            af3 = *reinterpret_cast<const short8*>(&Ab[r3 * 32 + (kc ^ (r3 & 3)) * 8]);
        }
        if (pf) STAGE_B(sb, (kt + 1) * 32);
        __builtin_amdgcn_s_barrier();
        asm volatile("s_waitcnt lgkmcnt(0)" ::: "memory");
        __builtin_amdgcn_sched_barrier(0);
        __builtin_amdgcn_s_setprio(1);
        #pragma unroll
        for (int ni = 0; ni < 4; ni++) {
            acc[2][ni] = __builtin_amdgcn_mfma_f32_16x16x32_bf16(af2, bf[ni], acc[2][ni], 0, 0, 0);
            acc[3][ni] = __builtin_amdgcn_mfma_f32_16x16x32_bf16(af3, bf[ni], acc[3][ni], 0, 0, 0);
        }
        __builtin_amdgcn_s_setprio(0);
        if (kt + 1 < KT)
            asm volatile("s_waitcnt vmcnt(0)" ::: "memory");   // next tile landed
        __builtin_amdgcn_s_barrier();
        __builtin_amdgcn_sched_barrier(0);

        cur ^= 1;
    }
#undef STAGE_A
#undef STAGE_B

    if (n0 >= 1536) {
        #pragma unroll
        for (int mi = 0; mi < 4; mi++) {
            int nn0g = m0 + wr * 64 + mi * 16 + org;
            int b = nn0g >> 10, nn = nn0g & 1023;
            #pragma unroll
            for (int ni = 0; ni < 4; ni++) {
                int colg = n0 + wc * 64 + ni * 16 + lr;
                int rem = colg - 1536;
                int h = rem >> 6, dd = rem & 63;
                float bv = bias[colg];
                unsigned long long u = 0;
                #pragma unroll
                for (int r = 0; r < 4; r++)
                    u |= (unsigned long long)f2bf(acc[mi][ni][r] + bv) << (16 * r);
                *reinterpret_cast<unsigned long long*>(
                    vo + ((size_t)(b * H_ + h) * HD + dd) * N_ + nn) = u;
            }
        }
    } else {
        int which = n0 / 768;
        unsigned short* dst = (which == 0) ? qo : ko;
        float fold = (which == 0) ? 0.125f * 1.44269504088896f : 1.0f;
        #pragma unroll
        for (int mi = 0; mi < 4; mi++) {
            #pragma unroll
            for (int ni = 0; ni < 4; ni++) {
                int col = n0 + wc * 64 + ni * 16 + lr;
                int rem = col - which * 768;
                int h = rem >> 6, dd = rem & 63;
                float bv = bias[col];
                #pragma unroll
                for (int r = 0; r < 4; r++) {
                    int row = m0 + wr * 64 + mi * 16 + org + r;
                    int b = row >> 10, nn = row & 1023;
                    dst[(((size_t)(b * H_ + h) * N_ + nn) * HD) + dd] =
                        f2bf((acc[mi][ni][r] + bv) * fold);
                }
            }
        }
    }
}

// ---------------- gemm<1> (proj): 64x128 tile, 768 blocks = 3/CU (r19) ------

__global__ __launch_bounds__(256) void gemm1_kernel(
    const unsigned short* __restrict__ A,
    const unsigned short* __restrict__ Bt,
    const float* __restrict__ bias,
    float* __restrict__ outf,
    int Ndim, int K)
{
    __shared__ alignas(16) unsigned short As[3 * 2048];
    __shared__ alignas(16) unsigned short Bs[3 * 4096];

    int tid = threadIdx.x;
    int lane = tid & 63, w = tid >> 6;

    int nbx = Ndim >> 7;
    int nwg = gridDim.x;
    int cpx = nwg >> 3;
    int sbid = (blockIdx.x & 7) * cpx + (blockIdx.x >> 3);
    int bx = sbid % nbx, by = sbid / nbx;
    int m0 = by * 64, n0 = bx * 128;

    int lr = lane & 15, lk8 = (lane >> 4) * 8;
    int org = (lane >> 4) * 4;

    int srow = tid >> 2;
    int selem = (tid & 3) * 8;
    const unsigned short* gA = A + (size_t)(m0 + srow) * K + selem;
    const unsigned short* gB = Bt + (size_t)(n0 + srow) * K + selem;

    f32x4 acc[4][2] = {};

#define GSTAGE(buf, k0)                                                    \
    do {                                                                   \
        gload16(gA + (k0), As + (buf) * 2048 + w * 512);                   \
        gload16(gB + (k0), Bs + (buf) * 4096 + w * 512);                   \
        gload16(gB + (size_t)64 * K + (k0), Bs + (buf) * 4096 + 2048 + w * 512);\
    } while (0)

    GSTAGE(0, 0);
    GSTAGE(1, 32);
    asm volatile("s_waitcnt vmcnt(3)" ::: "memory");
    __builtin_amdgcn_s_barrier();
    __builtin_amdgcn_sched_barrier(0);

    int KT = K >> 5;
    int cur = 0;
    for (int kt = 0; kt < KT; ++kt) {
        int sb = cur + 2; if (sb >= 3) sb -= 3;
        if (kt + 2 < KT) GSTAGE(sb, (kt + 2) * 32);

        const unsigned short* Ab = As + cur * 2048;
        const unsigned short* Bb = Bs + cur * 4096;
        short8 af[4], bf[2];
        #pragma unroll
        for (int mi = 0; mi < 4; mi++)
            af[mi] = *reinterpret_cast<const short8*>(&Ab[(mi * 16 + lr) * 32 + lk8]);
        #pragma unroll
        for (int ni = 0; ni < 2; ni++)
            bf[ni] = *reinterpret_cast<const short8*>(&Bb[(w * 32 + ni * 16 + lr) * 32 + lk8]);
        asm volatile("s_waitcnt lgkmcnt(0)" ::: "memory");
        __builtin_amdgcn_sched_barrier(0);
        #pragma unroll
        for (int mi = 0; mi < 4; mi++)
            #pragma unroll
            for (int ni = 0; ni < 2; ni++)
                acc[mi][ni] = __builtin_amdgcn_mfma_f32_16x16x32_bf16(bf[ni], af[mi], acc[mi][ni], 0, 0, 0);

        if (kt + 1 < KT) {
            if (kt + 2 < KT)
                asm volatile("s_waitcnt vmcnt(3)" ::: "memory");
            else
                asm volatile("s_waitcnt vmcnt(0)" ::: "memory");
            __builtin_amdgcn_s_barrier();
            __builtin_amdgcn_sched_barrier(0);
            cur = (cur == 2) ? 0 : cur + 1;
        }
    }
#undef GSTAGE

    int m = m0 + lr;
    #pragma unroll
    for (int mi = 0; mi < 4; mi++) {
        int row = m + mi * 16;
        #pragma unroll
        for (int ni = 0; ni < 2; ni++) {
            int col = n0 + w * 32 + ni * 16 + org;
            float4 bv = *reinterpret_cast<const float4*>(&bias[col]);
            float4 o;
            o.x = acc[mi][ni][0] + bv.x;
            o.y = acc[mi][ni][1] + bv.y;
            o.z = acc[mi][ni][2] + bv.z;
            o.w = acc[mi][ni][3] + bv.w;
            *reinterpret_cast<float4*>(&outf[(size_t)row * Ndim + col]) = o;
        }
    }
}

// ---------------- Flash attention (r16/r18 config — unchanged) --------------

__global__ __launch_bounds__(256) void attn_kernel(
    const unsigned short* __restrict__ qg,
    const unsigned short* __restrict__ kg,
    const unsigned short* __restrict__ vtg,
    unsigned short* __restrict__ aout)
{
    __shared__ alignas(16) unsigned short Ks[3][4096];
    __shared__ alignas(16) unsigned short Vs[3][4096];

    int tid = threadIdx.x;
    int lane = tid & 63, w = tid >> 6;

    int bid = blockIdx.x;
    int xcd = bid & 7;
    int chunk = bid >> 3;
    int bh = xcd * 12 + (chunk % 12);
    int qblk = chunk / 12;
    int b = bh / H_, h = bh - b * H_;
    int q0w = qblk * 128 + w * 32;
    int l31 = lane & 31;
    int hi = lane >> 5;
    int swz = l31 & 7;

    const unsigned short* qp = qg + ((size_t)bh * N_ + q0w + l31) * HD + hi * 8;
    short8 qf[4];
    #pragma unroll
    for (int ds = 0; ds < 4; ds++)
        qf[ds] = *reinterpret_cast<const short8*>(qp + ds * 16);

    const unsigned short* kbh = kg + (size_t)bh * N_ * HD;
    const unsigned short* vtbh = vtg + (size_t)bh * HD * N_;

    int sr0 = tid >> 3;
    int sj0 = (tid & 7) ^ (sr0 & 7);
    int sr1 = sr0 + 32;
    int sj1 = (tid & 7) ^ (sr1 & 7);

    float m_run = -INFINITY, l_run = 0.f;
    f32x16 o0 = {}, o1 = {};

#define STAGE(buf, kv0)                                                        \
    do {                                                                       \
        gload16(kbh + (size_t)((kv0) + sr0) * HD + sj0 * 8, &Ks[buf][w * 512]);\
        gload16(kbh + (size_t)((kv0) + sr1) * HD + sj1 * 8, &Ks[buf][2048 + w * 512]);\
        gload16(vtbh + (size_t)sr0 * N_ + (kv0) + sj0 * 8, &Vs[buf][w * 512]); \
        gload16(vtbh + (size_t)sr1 * N_ + (kv0) + sj1 * 8, &Vs[buf][2048 + w * 512]);\
    } while (0)

    STAGE(0, 0);
    STAGE(1, 64);
    asm volatile("s_waitcnt vmcnt(4)" ::: "memory");
    __builtin_amdgcn_s_barrier();
    __builtin_amdgcn_sched_barrier(0);

    int cur = 0;
    for (int t = 0; t < 16; ++t) {
        int sb = cur + 2; if (sb >= 3) sb -= 3;
        bool pf = (t + 2 < 16);
        if (pf) STAGE(sb, (t + 2) * 64);

        const unsigned short* Ksb = Ks[cur];
        const unsigned short* Vsb = Vs[cur];

        f32x16 s0 = {}, s1 = {};
        __builtin_amdgcn_s_setprio(1);
        #pragma unroll
        for (int ds = 0; ds < 4; ds++) {
            int pc = (ds * 2 + hi) ^ swz;
            short8 kf0 = *reinterpret_cast<const short8*>(&Ksb[(l31) * 64 + pc * 8]);
            short8 kf1 = *reinterpret_cast<const short8*>(&Ksb[(32 + l31) * 64 + pc * 8]);
            s0 = __builtin_amdgcn_mfma_f32_32x32x16_bf16(kf0, qf[ds], s0, 0, 0, 0);
            s1 = __builtin_amdgcn_mfma_f32_32x32x16_bf16(kf1, qf[ds], s1, 0, 0, 0);
        }
        __builtin_amdgcn_s_setprio(0);

        float mx = s0[0];
        #pragma unroll
        for (int r = 1; r < 16; r++) mx = fmaxf(mx, s0[r]);
        #pragma unroll
        for (int r = 0; r < 16; r++) mx = fmaxf(mx, s1[r]);
        mx = fmaxf(mx, __shfl_xor(mx, 32, 64));

        if (__any(mx > m_run + 8.f)) {
            float mn = fmaxf(m_run, mx);
            float al = exp2_hw(m_run - mn);
            m_run = mn;
            l_run *= al;
            o0 *= al;
            o1 *= al;
        }

        float psum = 0.f;
        #pragma unroll
        for (int r = 0; r < 16; r++) { float p = exp2_hw(s0[r] - m_run); psum += p; s0[r] = p; }
        #pragma unroll
        for (int r = 0; r < 16; r++) { float p = exp2_hw(s1[r] - m_run); psum += p; s1[r] = p; }

        l_run += psum + __shfl_xor(psum, 32, 64);

        unsigned int c0[8], c1[8];
        #pragma unroll
        for (int i = 0; i < 8; i++) c0[i] = cvtpk_bf16(s0[2 * i], s0[2 * i + 1]);
        #pragma unroll
        for (int i = 0; i < 8; i++) c1[i] = cvtpk_bf16(s1[2 * i], s1[2 * i + 1]);
        PLSWAP(c0[0], c0[2]); PLSWAP(c0[1], c0[3]);
        PLSWAP(c0[4], c0[6]); PLSWAP(c0[5], c0[7]);
        PLSWAP(c1[0], c1[2]); PLSWAP(c1[1], c1[3]);
        PLSWAP(c1[4], c1[6]); PLSWAP(c1[5], c1[7]);
        short8 pa0 = pack4(c0[0], c0[1], c0[2], c0[3]);
        short8 pa1 = pack4(c0[4], c0[5], c0[6], c0[7]);
        short8 pa2 = pack4(c1[0], c1[1], c1[2], c1[3]);
        short8 pa3 = pack4(c1[4], c1[5], c1[6], c1[7]);

        __builtin_amdgcn_s_setprio(1);
        #pragma unroll
        for (int ks = 0; ks < 4; ks++) {
            int pc = (ks * 2 + hi) ^ swz;
            short8 vf0 = *reinterpret_cast<const short8*>(&Vsb[(l31) * 64 + pc * 8]);
            short8 vf1 = *reinterpret_cast<const short8*>(&Vsb[(32 + l31) * 64 + pc * 8]);
            short8 pa = (ks == 0) ? pa0 : (ks == 1) ? pa1 : (ks == 2) ? pa2 : pa3;
            o0 = __builtin_amdgcn_mfma_f32_32x32x16_bf16(vf0, pa, o0, 0, 0, 0);
            o1 = __builtin_amdgcn_mfma_f32_32x32x16_bf16(vf1, pa, o1, 0, 0, 0);
        }
        __builtin_amdgcn_s_setprio(0);

        if (t < 15) {
            if (pf) asm volatile("s_waitcnt vmcnt(4)" ::: "memory");
            else    asm volatile("s_waitcnt vmcnt(0)" ::: "memory");
            __builtin_amdgcn_s_barrier();
            __builtin_amdgcn_sched_barrier(0);
            cur = (cur == 2) ? 0 : cur + 1;
        }
    }
#undef STAGE

    float linv = 1.0f / l_run;
    unsigned short* op = aout + ((size_t)(b * N_ + q0w + l31)) * D_ + h * HD;
    #pragma unroll
    for (int rg = 0; rg < 4; rg++) {
        int dbase = 8 * rg + 4 * hi;
        unsigned long long u0 = 0, u1 = 0;
        #pragma unroll
        for (int k = 0; k < 4; k++) {
            u0 |= (unsigned long long)f2bf(o0[rg * 4 + k] * linv) << (16 * k);
            u1 |= (unsigned long long)f2bf(o1[rg * 4 + k] * linv) << (16 * k);
        }
        *reinterpret_cast<unsigned long long*>(op + dbase) = u0;
        *reinterpret_cast<unsigned long long*>(op + 32 + dbase) = u1;
    }
}

// ---------------- launch ----------------

extern "C" void kernel_launch(void* const* d_in, const int* in_sizes, int n_in,
                              void* d_out, int out_size, void* d_ws, size_t ws_size,
                              hipStream_t stream) {
    const float* x      = (const float*)d_in[0];
    const float* w_qkv  = (const float*)d_in[1];
    const float* b_qkv  = (const float*)d_in[2];
    const float* w_proj = (const float*)d_in[3];
    const float* b_proj = (const float*)d_in[4];
    float* out = (float*)d_out;

    char* ws = (char*)d_ws;
    unsigned short* xb     = (unsigned short*)(ws + 0);
    unsigned short* wqkvT  = (unsigned short*)(ws + 12582912);
    unsigned short* wprojT = (unsigned short*)(ws + 16121856);
    unsigned short* qb     = (unsigned short*)(ws + 17301504);
    unsigned short* kb     = (unsigned short*)(ws + 29884416);
    unsigned short* vtb    = (unsigned short*)(ws + 42467328);
    unsigned short* aout   = xb;

    prep_kernel<<<3648, 256, 0, stream>>>(x, w_qkv, w_proj, xb, wqkvT, wprojT);

    gemm0_kernel<<<dim3(18, 32), 512, 0, stream>>>(
        xb, wqkvT, b_qkv, qb, kb, vtb);

    attn_kernel<<<768, 256, 0, stream>>>(qb, kb, vtb, aout);

    gemm1_kernel<<<768, 256, 0, stream>>>(
        aout, wprojT, b_proj, out, D_, D_);
}

// Round 21
// 129.153 us; speedup vs baseline: 2.1211x; 2.1211x over previous
//
#include <hip/hip_runtime.h>

#define B_ 8
#define N_ 1024
#define D_ 768
#define H_ 12
#define HD 64
#define M_ (B_*N_)

typedef short short8 __attribute__((ext_vector_type(8)));
typedef float f32x4 __attribute__((ext_vector_type(4)));
typedef float f32x16 __attribute__((ext_vector_type(16)));
typedef int int4v __attribute__((ext_vector_type(4)));

__device__ __forceinline__ unsigned short f2bf(float f) {
    union { float f; unsigned int u; } c; c.f = f;
    unsigned int u = c.u;
    unsigned int r = (u + 0x7fffu + ((u >> 16) & 1u)) >> 16;
    return (unsigned short)r;
}

__device__ __forceinline__ float exp2_hw(float x) {
    float r;
    asm("v_exp_f32 %0, %1" : "=v"(r) : "v"(x));
    return r;
}

__device__ __forceinline__ unsigned int cvtpk_bf16(float a, float b) {
    unsigned int r;
    asm("v_cvt_pk_bf16_f32 %0, %1, %2" : "=v"(r) : "v"(a), "v"(b));
    return r;
}

// swap a's lanes32-63 with b's lanes0-31. "+&v" early-clobber forces distinct
// VGPRs (plain "+v" lets the allocator coalesce equal-valued operands — r5 bug).
#define PLSWAP(a, b) asm volatile("v_permlane32_swap_b32 %0, %1" : "+&v"(a), "+&v"(b))

__device__ __forceinline__ short8 pack4(unsigned int a, unsigned int b,
                                        unsigned int c, unsigned int d) {
    union { int4v i; short8 s; } u;
    u.i = (int4v){(int)a, (int)b, (int)c, (int)d};
    return u.s;
}

__device__ __forceinline__ void gload16(const void* g, void* l) {
    __builtin_amdgcn_global_load_lds(
        (const __attribute__((address_space(1))) unsigned int*)g,
        (__attribute__((address_space(3))) unsigned int*)l, 16, 0, 0);
}

// ---------------- fused prep: cast x (32B/thread); LDS-tiled W transpose ----

__global__ __launch_bounds__(256) void prep_kernel(
    const float* __restrict__ x, const float* __restrict__ wqkv,
    const float* __restrict__ wproj,
    unsigned short* __restrict__ xb, unsigned short* __restrict__ wqkvT,
    unsigned short* __restrict__ wprojT)
{
    int bid = blockIdx.x, tid = threadIdx.x;
    if (bid < 3072) {
        int i = (bid * 256 + tid) * 2;
        float4 v0 = reinterpret_cast<const float4*>(x)[i];
        float4 v1 = reinterpret_cast<const float4*>(x)[i + 1];
        ushort4 o0, o1;
        o0.x = f2bf(v0.x); o0.y = f2bf(v0.y); o0.z = f2bf(v0.z); o0.w = f2bf(v0.w);
        o1.x = f2bf(v1.x); o1.y = f2bf(v1.y); o1.z = f2bf(v1.z); o1.w = f2bf(v1.w);
        reinterpret_cast<ushort4*>(xb)[i] = o0;
        reinterpret_cast<ushort4*>(xb)[i + 1] = o1;
        return;
    }
    __shared__ unsigned short T[64][72];
    const float* W; unsigned short* wT; int Rr, Cc, idx;
    if (bid < 3072 + 432) { W = wqkv;  wT = wqkvT;  Rr = 768; Cc = 2304; idx = bid - 3072; }
    else                  { W = wproj; wT = wprojT; Rr = 768; Cc = 768;  idx = bid - 3504; }
    int ntc = Cc >> 6;
    int tc = idx % ntc, tr = idx / ntc;
    int r0 = tr * 64, c0 = tc * 64;
    {
        int row = tid >> 2, cg = (tid & 3) * 16;
        const float4* src = reinterpret_cast<const float4*>(&W[(size_t)(r0 + row) * Cc + c0 + cg]);
        ushort4 o[4];
        #pragma unroll
        for (int j = 0; j < 4; j++) {
            float4 v = src[j];
            o[j].x = f2bf(v.x); o[j].y = f2bf(v.y); o[j].z = f2bf(v.z); o[j].w = f2bf(v.w);
        }
        #pragma unroll
        for (int j = 0; j < 4; j++)
            *reinterpret_cast<ushort4*>(&T[row][cg + j * 4]) = o[j];
    }
    __syncthreads();
    {
        int orow = tid >> 2, rg = (tid & 3) * 16;
        unsigned short tmp[16];
        #pragma unroll
        for (int j = 0; j < 16; j++) tmp[j] = T[rg + j][orow];
        uint4* dst = reinterpret_cast<uint4*>(&wT[(size_t)(c0 + orow) * Rr + r0 + rg]);
        dst[0] = *reinterpret_cast<const uint4*>(&tmp[0]);
        dst[1] = *reinterpret_cast<const uint4*>(&tmp[8]);
    }
}

// ---------------- gemm<0>: 256x128, 8 waves, BK=32, DEPTH-2, PHASE-SPLIT ----
// r21: depth-2 retry with launch_bounds(512,4). r20's (512,6) capped the
// allocator at 40 VGPR -> acc[4][4] spilled to scratch (FETCH 336 MB, 210 us).
// With (512,4) the kernel keeps VGPR 64 (fits 8 waves/SIMD) and the only
// occupancy limiter is LDS: 48 KB -> 3 blocks/CU -> all 576 blocks resident
// (r19's 72 KB depth-3 capped at 2/CU -> 64-block straggler wave).
// Phase-split + setprio + sched_barrier discipline unchanged (r16-proven).

__global__ __launch_bounds__(512, 4) void gemm0_kernel(
    const unsigned short* __restrict__ A,
    const unsigned short* __restrict__ Bt,
    const float* __restrict__ bias,
    unsigned short* __restrict__ qo,
    unsigned short* __restrict__ ko,
    unsigned short* __restrict__ vo)
{
    const int K = D_;                       // 768
    const int KT = K >> 5;                  // 24
    __shared__ alignas(16) unsigned short As[2 * 8192];   // 32 KB
    __shared__ alignas(16) unsigned short Bs[2 * 4096];   // 16 KB

    int tid = threadIdx.x;
    int lane = tid & 63, w = tid >> 6;
    int wr = w >> 1, wc = w & 1;

    int m0 = blockIdx.y * 256, n0 = blockIdx.x * 128;

    int lr = lane & 15;
    int kc = lane >> 4;
    int org = (lane >> 4) * 4;

    int srA = w * 16 + (lane >> 2);
    int scA0 = (lane & 3) ^ (srA & 3);
    int srA1 = 128 + srA;
    int scA1 = (lane & 3) ^ (srA1 & 3);
    const unsigned short* gA0 = A + (size_t)(m0 + srA) * K + scA0 * 8;
    const unsigned short* gA1 = A + (size_t)(m0 + srA1) * K + scA1 * 8;
    const unsigned short* gB0 = Bt + (size_t)(n0 + srA) * K + scA0 * 8;

    f32x4 acc[4][4] = {};

#define STAGE_A(buf, k0)                                                   \
    do {                                                                   \
        gload16(gA0 + (k0), As + (buf) * 8192 + w * 512);                  \
        gload16(gA1 + (k0), As + (buf) * 8192 + 4096 + w * 512);           \
    } while (0)
#define STAGE_B(buf, k0) gload16(gB0 + (k0), Bs + (buf) * 4096 + w * 512)

    STAGE_A(0, 0); STAGE_B(0, 0);
    asm volatile("s_waitcnt vmcnt(0)" ::: "memory");
    __builtin_amdgcn_s_barrier();
    __builtin_amdgcn_sched_barrier(0);

    int cur = 0;
    for (int kt = 0; kt < KT; ++kt) {
        int sb = cur ^ 1;
        bool pf = (kt + 1 < KT);
        const unsigned short* Ab = As + cur * 8192;
        const unsigned short* Bb = Bs + cur * 4096;

        // ---- phase 0: A-frags m0,m1 + all B-frags; stage A of kt+1 ----
        short8 af0, af1, bf[4];
        {
            int r0 = wr * 64 + lr;
            int r1 = wr * 64 + 16 + lr;
            af0 = *reinterpret_cast<const short8*>(&Ab[r0 * 32 + (kc ^ (r0 & 3)) * 8]);
            af1 = *reinterpret_cast<const short8*>(&Ab[r1 * 32 + (kc ^ (r1 & 3)) * 8]);
            #pragma unroll
            for (int ni = 0; ni < 4; ni++) {
                int rb = wc * 64 + ni * 16 + lr;
                bf[ni] = *reinterpret_cast<const short8*>(&Bb[rb * 32 + (kc ^ (rb & 3)) * 8]);
            }
        }
        if (pf) STAGE_A(sb, (kt + 1) * 32);
        __builtin_amdgcn_s_barrier();
        asm volatile("s_waitcnt lgkmcnt(0)" ::: "memory");
        __builtin_amdgcn_sched_barrier(0);
        __builtin_amdgcn_s_setprio(1);
        #pragma unroll
        for (int ni = 0; ni < 4; ni++) {
            acc[0][ni] = __builtin_amdgcn_mfma_f32_16x16x32_bf16(af0, bf[ni], acc[0][ni], 0, 0, 0);
            acc[1][ni] = __builtin_amdgcn_mfma_f32_16x16x32_bf16(af1, bf[ni], acc[1][ni], 0, 0, 0);
        }
        __builtin_amdgcn_s_setprio(0);
        __builtin_amdgcn_s_barrier();
        __builtin_amdgcn_sched_barrier(0);

        // ---- phase 1: A-frags m2,m3; stage B of kt+1; end-of-tile drain ----
        short8 af2, af3;
        {
            int r2 = wr * 64 + 32 + lr;
            int r3 = wr * 64 + 48 + lr;
            af2 = *reinterpret_cast<const short8*>(&Ab[r2 * 32 + (kc ^ (r2 & 3)) * 8]);
            af3 = *reinterpret_cast<const short8*>(&Ab[r3 * 32 + (kc ^ (r3 & 3)) * 8]);
        }
        if (pf) STAGE_B(sb, (kt + 1) * 32);
        __builtin_amdgcn_s_barrier();
        asm volatile("s_waitcnt lgkmcnt(0)" ::: "memory");
        __builtin_amdgcn_sched_barrier(0);
        __builtin_amdgcn_s_setprio(1);
        #pragma unroll
        for (int ni = 0; ni < 4; ni++) {
            acc[2][ni] = __builtin_amdgcn_mfma_f32_16x16x32_bf16(af2, bf[ni], acc[2][ni], 0, 0, 0);
            acc[3][ni] = __builtin_amdgcn_mfma_f32_16x16x32_bf16(af3, bf[ni], acc[3][ni], 0, 0, 0);
        }
        __builtin_amdgcn_s_setprio(0);
        if (kt + 1 < KT)
            asm volatile("s_waitcnt vmcnt(0)" ::: "memory");   // next tile landed
        __builtin_amdgcn_s_barrier();
        __builtin_amdgcn_sched_barrier(0);

        cur ^= 1;
    }
#undef STAGE_A
#undef STAGE_B

    if (n0 >= 1536) {
        #pragma unroll
        for (int mi = 0; mi < 4; mi++) {
            int nn0g = m0 + wr * 64 + mi * 16 + org;
            int b = nn0g >> 10, nn = nn0g & 1023;
            #pragma unroll
            for (int ni = 0; ni < 4; ni++) {
                int colg = n0 + wc * 64 + ni * 16 + lr;
                int rem = colg - 1536;
                int h = rem >> 6, dd = rem & 63;
                float bv = bias[colg];
                unsigned long long u = 0;
                #pragma unroll
                for (int r = 0; r < 4; r++)
                    u |= (unsigned long long)f2bf(acc[mi][ni][r] + bv) << (16 * r);
                *reinterpret_cast<unsigned long long*>(
                    vo + ((size_t)(b * H_ + h) * HD + dd) * N_ + nn) = u;
            }
        }
    } else {
        int which = n0 / 768;
        unsigned short* dst = (which == 0) ? qo : ko;
        float fold = (which == 0) ? 0.125f * 1.44269504088896f : 1.0f;
        #pragma unroll
        for (int mi = 0; mi < 4; mi++) {
            #pragma unroll
            for (int ni = 0; ni < 4; ni++) {
                int col = n0 + wc * 64 + ni * 16 + lr;
                int rem = col - which * 768;
                int h = rem >> 6, dd = rem & 63;
                float bv = bias[col];
                #pragma unroll
                for (int r = 0; r < 4; r++) {
                    int row = m0 + wr * 64 + mi * 16 + org + r;
                    int b = row >> 10, nn = row & 1023;
                    dst[(((size_t)(b * H_ + h) * N_ + nn) * HD) + dd] =
                        f2bf((acc[mi][ni][r] + bv) * fold);
                }
            }
        }
    }
}

// ---------------- gemm<1> (proj): 64x128 tile, 768 blocks = 3/CU (r19) ------

__global__ __launch_bounds__(256) void gemm1_kernel(
    const unsigned short* __restrict__ A,
    const unsigned short* __restrict__ Bt,
    const float* __restrict__ bias,
    float* __restrict__ outf,
    int Ndim, int K)
{
    __shared__ alignas(16) unsigned short As[3 * 2048];
    __shared__ alignas(16) unsigned short Bs[3 * 4096];

    int tid = threadIdx.x;
    int lane = tid & 63, w = tid >> 6;

    int nbx = Ndim >> 7;
    int nwg = gridDim.x;
    int cpx = nwg >> 3;
    int sbid = (blockIdx.x & 7) * cpx + (blockIdx.x >> 3);
    int bx = sbid % nbx, by = sbid / nbx;
    int m0 = by * 64, n0 = bx * 128;

    int lr = lane & 15, lk8 = (lane >> 4) * 8;
    int org = (lane >> 4) * 4;

    int srow = tid >> 2;
    int selem = (tid & 3) * 8;
    const unsigned short* gA = A + (size_t)(m0 + srow) * K + selem;
    const unsigned short* gB = Bt + (size_t)(n0 + srow) * K + selem;

    f32x4 acc[4][2] = {};

#define GSTAGE(buf, k0)                                                    \
    do {                                                                   \
        gload16(gA + (k0), As + (buf) * 2048 + w * 512);                   \
        gload16(gB + (k0), Bs + (buf) * 4096 + w * 512);                   \
        gload16(gB + (size_t)64 * K + (k0), Bs + (buf) * 4096 + 2048 + w * 512);\
    } while (0)

    GSTAGE(0, 0);
    GSTAGE(1, 32);
    asm volatile("s_waitcnt vmcnt(3)" ::: "memory");
    __builtin_amdgcn_s_barrier();
    __builtin_amdgcn_sched_barrier(0);

    int KT = K >> 5;
    int cur = 0;
    for (int kt = 0; kt < KT; ++kt) {
        int sb = cur + 2; if (sb >= 3) sb -= 3;
        if (kt + 2 < KT) GSTAGE(sb, (kt + 2) * 32);

        const unsigned short* Ab = As + cur * 2048;
        const unsigned short* Bb = Bs + cur * 4096;
        short8 af[4], bf[2];
        #pragma unroll
        for (int mi = 0; mi < 4; mi++)
            af[mi] = *reinterpret_cast<const short8*>(&Ab[(mi * 16 + lr) * 32 + lk8]);
        #pragma unroll
        for (int ni = 0; ni < 2; ni++)
            bf[ni] = *reinterpret_cast<const short8*>(&Bb[(w * 32 + ni * 16 + lr) * 32 + lk8]);
        asm volatile("s_waitcnt lgkmcnt(0)" ::: "memory");
        __builtin_amdgcn_sched_barrier(0);
        #pragma unroll
        for (int mi = 0; mi < 4; mi++)
            #pragma unroll
            for (int ni = 0; ni < 2; ni++)
                acc[mi][ni] = __builtin_amdgcn_mfma_f32_16x16x32_bf16(bf[ni], af[mi], acc[mi][ni], 0, 0, 0);

        if (kt + 1 < KT) {
            if (kt + 2 < KT)
                asm volatile("s_waitcnt vmcnt(3)" ::: "memory");
            else
                asm volatile("s_waitcnt vmcnt(0)" ::: "memory");
            __builtin_amdgcn_s_barrier();
            __builtin_amdgcn_sched_barrier(0);
            cur = (cur == 2) ? 0 : cur + 1;
        }
    }
#undef GSTAGE

    int m = m0 + lr;
    #pragma unroll
    for (int mi = 0; mi < 4; mi++) {
        int row = m + mi * 16;
        #pragma unroll
        for (int ni = 0; ni < 2; ni++) {
            int col = n0 + w * 32 + ni * 16 + org;
            float4 bv = *reinterpret_cast<const float4*>(&bias[col]);
            float4 o;
            o.x = acc[mi][ni][0] + bv.x;
            o.y = acc[mi][ni][1] + bv.y;
            o.z = acc[mi][ni][2] + bv.z;
            o.w = acc[mi][ni][3] + bv.w;
            *reinterpret_cast<float4*>(&outf[(size_t)row * Ndim + col]) = o;
        }
    }
}

// ---------------- Flash attention (r16/r18 config — unchanged) --------------

__global__ __launch_bounds__(256) void attn_kernel(
    const unsigned short* __restrict__ qg,
    const unsigned short* __restrict__ kg,
    const unsigned short* __restrict__ vtg,
    unsigned short* __restrict__ aout)
{
    __shared__ alignas(16) unsigned short Ks[3][4096];
    __shared__ alignas(16) unsigned short Vs[3][4096];

    int tid = threadIdx.x;
    int lane = tid & 63, w = tid >> 6;

    int bid = blockIdx.x;
    int xcd = bid & 7;
    int chunk = bid >> 3;
    int bh = xcd * 12 + (chunk % 12);
    int qblk = chunk / 12;
    int b = bh / H_, h = bh - b * H_;
    int q0w = qblk * 128 + w * 32;
    int l31 = lane & 31;
    int hi = lane >> 5;
    int swz = l31 & 7;

    const unsigned short* qp = qg + ((size_t)bh * N_ + q0w + l31) * HD + hi * 8;
    short8 qf[4];
    #pragma unroll
    for (int ds = 0; ds < 4; ds++)
        qf[ds] = *reinterpret_cast<const short8*>(qp + ds * 16);

    const unsigned short* kbh = kg + (size_t)bh * N_ * HD;
    const unsigned short* vtbh = vtg + (size_t)bh * HD * N_;

    int sr0 = tid >> 3;
    int sj0 = (tid & 7) ^ (sr0 & 7);
    int sr1 = sr0 + 32;
    int sj1 = (tid & 7) ^ (sr1 & 7);

    float m_run = -INFINITY, l_run = 0.f;
    f32x16 o0 = {}, o1 = {};

#define STAGE(buf, kv0)                                                        \
    do {                                                                       \
        gload16(kbh + (size_t)((kv0) + sr0) * HD + sj0 * 8, &Ks[buf][w * 512]);\
        gload16(kbh + (size_t)((kv0) + sr1) * HD + sj1 * 8, &Ks[buf][2048 + w * 512]);\
        gload16(vtbh + (size_t)sr0 * N_ + (kv0) + sj0 * 8, &Vs[buf][w * 512]); \
        gload16(vtbh + (size_t)sr1 * N_ + (kv0) + sj1 * 8, &Vs[buf][2048 + w * 512]);\
    } while (0)

    STAGE(0, 0);
    STAGE(1, 64);
    asm volatile("s_waitcnt vmcnt(4)" ::: "memory");
    __builtin_amdgcn_s_barrier();
    __builtin_amdgcn_sched_barrier(0);

    int cur = 0;
    for (int t = 0; t < 16; ++t) {
        int sb = cur + 2; if (sb >= 3) sb -= 3;
        bool pf = (t + 2 < 16);
        if (pf) STAGE(sb, (t + 2) * 64);

        const unsigned short* Ksb = Ks[cur];
        const unsigned short* Vsb = Vs[cur];

        f32x16 s0 = {}, s1 = {};
        __builtin_amdgcn_s_setprio(1);
        #pragma unroll
        for (int ds = 0; ds < 4; ds++) {
            int pc = (ds * 2 + hi) ^ swz;
            short8 kf0 = *reinterpret_cast<const short8*>(&Ksb[(l31) * 64 + pc * 8]);
            short8 kf1 = *reinterpret_cast<const short8*>(&Ksb[(32 + l31) * 64 + pc * 8]);
            s0 = __builtin_amdgcn_mfma_f32_32x32x16_bf16(kf0, qf[ds], s0, 0, 0, 0);
            s1 = __builtin_amdgcn_mfma_f32_32x32x16_bf16(kf1, qf[ds], s1, 0, 0, 0);
        }
        __builtin_amdgcn_s_setprio(0);

        float mx = s0[0];
        #pragma unroll
        for (int r = 1; r < 16; r++) mx = fmaxf(mx, s0[r]);
        #pragma unroll
        for (int r = 0; r < 16; r++) mx = fmaxf(mx, s1[r]);
        mx = fmaxf(mx, __shfl_xor(mx, 32, 64));

        if (__any(mx > m_run + 8.f)) {
            float mn = fmaxf(m_run, mx);
            float al = exp2_hw(m_run - mn);
            m_run = mn;
            l_run *= al;
            o0 *= al;
            o1 *= al;
        }

        float psum = 0.f;
        #pragma unroll
        for (int r = 0; r < 16; r++) { float p = exp2_hw(s0[r] - m_run); psum += p; s0[r] = p; }
        #pragma unroll
        for (int r = 0; r < 16; r++) { float p = exp2_hw(s1[r] - m_run); psum += p; s1[r] = p; }

        l_run += psum + __shfl_xor(psum, 32, 64);

        unsigned int c0[8], c1[8];
        #pragma unroll
        for (int i = 0; i < 8; i++) c0[i] = cvtpk_bf16(s0[2 * i], s0[2 * i + 1]);
        #pragma unroll
        for (int i = 0; i < 8; i++) c1[i] = cvtpk_bf16(s1[2 * i], s1[2 * i + 1]);
        PLSWAP(c0[0], c0[2]); PLSWAP(c0[1], c0[3]);
        PLSWAP(c0[4], c0[6]); PLSWAP(c0[5], c0[7]);
        PLSWAP(c1[0], c1[2]); PLSWAP(c1[1], c1[3]);
        PLSWAP(c1[4], c1[6]); PLSWAP(c1[5], c1[7]);
        short8 pa0 = pack4(c0[0], c0[1], c0[2], c0[3]);
        short8 pa1 = pack4(c0[4], c0[5], c0[6], c0[7]);
        short8 pa2 = pack4(c1[0], c1[1], c1[2], c1[3]);
        short8 pa3 = pack4(c1[4], c1[5], c1[6], c1[7]);

        __builtin_amdgcn_s_setprio(1);
        #pragma unroll
        for (int ks = 0; ks < 4; ks++) {
            int pc = (ks * 2 + hi) ^ swz;
            short8 vf0 = *reinterpret_cast<const short8*>(&Vsb[(l31) * 64 + pc * 8]);
            short8 vf1 = *reinterpret_cast<const short8*>(&Vsb[(32 + l31) * 64 + pc * 8]);
            short8 pa = (ks == 0) ? pa0 : (ks == 1) ? pa1 : (ks == 2) ? pa2 : pa3;
            o0 = __builtin_amdgcn_mfma_f32_32x32x16_bf16(vf0, pa, o0, 0, 0, 0);
            o1 = __builtin_amdgcn_mfma_f32_32x32x16_bf16(vf1, pa, o1, 0, 0, 0);
        }
        __builtin_amdgcn_s_setprio(0);

        if (t < 15) {
            if (pf) asm volatile("s_waitcnt vmcnt(4)" ::: "memory");
            else    asm volatile("s_waitcnt vmcnt(0)" ::: "memory");
            __builtin_amdgcn_s_barrier();
            __builtin_amdgcn_sched_barrier(0);
            cur = (cur == 2) ? 0 : cur + 1;
        }
    }
#undef STAGE

    float linv = 1.0f / l_run;
    unsigned short* op = aout + ((size_t)(b * N_ + q0w + l31)) * D_ + h * HD;
    #pragma unroll
    for (int rg = 0; rg < 4; rg++) {
        int dbase = 8 * rg + 4 * hi;
        unsigned long long u0 = 0, u1 = 0;
        #pragma unroll
        for (int k = 0; k < 4; k++) {
            u0 |= (unsigned long long)f2bf(o0[rg * 4 + k] * linv) << (16 * k);
            u1 |= (unsigned long long)f2bf(o1[rg * 4 + k] * linv) << (16 * k);
        }
        *reinterpret_cast<unsigned long long*>(op + dbase) = u0;
        *reinterpret_cast<unsigned long long*>(op + 32 + dbase) = u1;
    }
}

// ---------------- launch ----------------

extern "C" void kernel_launch(void* const* d_in, const int* in_sizes, int n_in,
                              void* d_out, int out_size, void* d_ws, size_t ws_size,
                              hipStream_t stream) {
    const float* x      = (const float*)d_in[0];
    const float* w_qkv  = (const float*)d_in[1];
    const float* b_qkv  = (const float*)d_in[2];
    const float* w_proj = (const float*)d_in[3];
    const float* b_proj = (const float*)d_in[4];
    float* out = (float*)d_out;

    char* ws = (char*)d_ws;
    unsigned short* xb     = (unsigned short*)(ws + 0);
    unsigned short* wqkvT  = (unsigned short*)(ws + 12582912);
    unsigned short* wprojT = (unsigned short*)(ws + 16121856);
    unsigned short* qb     = (unsigned short*)(ws + 17301504);
    unsigned short* kb     = (unsigned short*)(ws + 29884416);
    unsigned short* vtb    = (unsigned short*)(ws + 42467328);
    unsigned short* aout   = xb;

    prep_kernel<<<3648, 256, 0, stream>>>(x, w_qkv, w_proj, xb, wqkvT, wprojT);

    gemm0_kernel<<<dim3(18, 32), 512, 0, stream>>>(
        xb, wqkvT, b_qkv, qb, kb, vtb);

    attn_kernel<<<768, 256, 0, stream>>>(qb, kb, vtb, aout);

    gemm1_kernel<<<768, 256, 0, stream>>>(
        aout, wprojT, b_proj, out, D_, D_);
}

// Round 22
// 126.345 us; speedup vs baseline: 2.1683x; 1.0222x over previous
//
#include <hip/hip_runtime.h>

#define B_ 8
#define N_ 1024
#define D_ 768
#define H_ 12
#define HD 64
#define M_ (B_*N_)

typedef short short8 __attribute__((ext_vector_type(8)));
typedef float f32x4 __attribute__((ext_vector_type(4)));
typedef float f32x16 __attribute__((ext_vector_type(16)));
typedef int int4v __attribute__((ext_vector_type(4)));

__device__ __forceinline__ unsigned short f2bf(float f) {
    union { float f; unsigned int u; } c; c.f = f;
    unsigned int u = c.u;
    unsigned int r = (u + 0x7fffu + ((u >> 16) & 1u)) >> 16;
    return (unsigned short)r;
}

__device__ __forceinline__ float exp2_hw(float x) {
    float r;
    asm("v_exp_f32 %0, %1" : "=v"(r) : "v"(x));
    return r;
}

__device__ __forceinline__ unsigned int cvtpk_bf16(float a, float b) {
    unsigned int r;
    asm("v_cvt_pk_bf16_f32 %0, %1, %2" : "=v"(r) : "v"(a), "v"(b));
    return r;
}

// swap a's lanes32-63 with b's lanes0-31. "+&v" early-clobber forces distinct
// VGPRs (plain "+v" lets the allocator coalesce equal-valued operands — r5 bug).
#define PLSWAP(a, b) asm volatile("v_permlane32_swap_b32 %0, %1" : "+&v"(a), "+&v"(b))

__device__ __forceinline__ short8 pack4(unsigned int a, unsigned int b,
                                        unsigned int c, unsigned int d) {
    union { int4v i; short8 s; } u;
    u.i = (int4v){(int)a, (int)b, (int)c, (int)d};
    return u.s;
}

__device__ __forceinline__ void gload16(const void* g, void* l) {
    __builtin_amdgcn_global_load_lds(
        (const __attribute__((address_space(1))) unsigned int*)g,
        (__attribute__((address_space(3))) unsigned int*)l, 16, 0, 0);
}

// ---------------- fused prep: cast x (32B/thread); LDS-tiled W transpose ----

__global__ __launch_bounds__(256) void prep_kernel(
    const float* __restrict__ x, const float* __restrict__ wqkv,
    const float* __restrict__ wproj,
    unsigned short* __restrict__ xb, unsigned short* __restrict__ wqkvT,
    unsigned short* __restrict__ wprojT)
{
    int bid = blockIdx.x, tid = threadIdx.x;
    if (bid < 3072) {
        int i = (bid * 256 + tid) * 2;
        float4 v0 = reinterpret_cast<const float4*>(x)[i];
        float4 v1 = reinterpret_cast<const float4*>(x)[i + 1];
        ushort4 o0, o1;
        o0.x = f2bf(v0.x); o0.y = f2bf(v0.y); o0.z = f2bf(v0.z); o0.w = f2bf(v0.w);
        o1.x = f2bf(v1.x); o1.y = f2bf(v1.y); o1.z = f2bf(v1.z); o1.w = f2bf(v1.w);
        reinterpret_cast<ushort4*>(xb)[i] = o0;
        reinterpret_cast<ushort4*>(xb)[i + 1] = o1;
        return;
    }
    __shared__ unsigned short T[64][72];
    const float* W; unsigned short* wT; int Rr, Cc, idx;
    if (bid < 3072 + 432) { W = wqkv;  wT = wqkvT;  Rr = 768; Cc = 2304; idx = bid - 3072; }
    else                  { W = wproj; wT = wprojT; Rr = 768; Cc = 768;  idx = bid - 3504; }
    int ntc = Cc >> 6;
    int tc = idx % ntc, tr = idx / ntc;
    int r0 = tr * 64, c0 = tc * 64;
    {
        int row = tid >> 2, cg = (tid & 3) * 16;
        const float4* src = reinterpret_cast<const float4*>(&W[(size_t)(r0 + row) * Cc + c0 + cg]);
        ushort4 o[4];
        #pragma unroll
        for (int j = 0; j < 4; j++) {
            float4 v = src[j];
            o[j].x = f2bf(v.x); o[j].y = f2bf(v.y); o[j].z = f2bf(v.z); o[j].w = f2bf(v.w);
        }
        #pragma unroll
        for (int j = 0; j < 4; j++)
            *reinterpret_cast<ushort4*>(&T[row][cg + j * 4]) = o[j];
    }
    __syncthreads();
    {
        int orow = tid >> 2, rg = (tid & 3) * 16;
        unsigned short tmp[16];
        #pragma unroll
        for (int j = 0; j < 16; j++) tmp[j] = T[rg + j][orow];
        uint4* dst = reinterpret_cast<uint4*>(&wT[(size_t)(c0 + orow) * Rr + r0 + rg]);
        dst[0] = *reinterpret_cast<const uint4*>(&tmp[0]);
        dst[1] = *reinterpret_cast<const uint4*>(&tmp[8]);
    }
}

// ---------------- gemm<0>: 256x128, 8 waves, BK=32, DEPTH-3, PHASE-SPLIT ----
// r19 config verbatim — session optimum (54.4 us, reproduced 3x). Depth-2
// (r21: 57.7-59.4) and merged-phase (r17: 59.4) both measured worse.
// sched_barrier(0) after every s_barrier (r14 race lesson).

__global__ __launch_bounds__(512, 4) void gemm0_kernel(
    const unsigned short* __restrict__ A,
    const unsigned short* __restrict__ Bt,
    const float* __restrict__ bias,
    unsigned short* __restrict__ qo,
    unsigned short* __restrict__ ko,
    unsigned short* __restrict__ vo)
{
    const int K = D_;                       // 768
    const int KT = K >> 5;                  // 24
    __shared__ alignas(16) unsigned short As[3 * 8192];
    __shared__ alignas(16) unsigned short Bs[3 * 4096];

    int tid = threadIdx.x;
    int lane = tid & 63, w = tid >> 6;
    int wr = w >> 1, wc = w & 1;

    int m0 = blockIdx.y * 256, n0 = blockIdx.x * 128;

    int lr = lane & 15;
    int kc = lane >> 4;
    int org = (lane >> 4) * 4;

    int srA = w * 16 + (lane >> 2);
    int scA0 = (lane & 3) ^ (srA & 3);
    int srA1 = 128 + srA;
    int scA1 = (lane & 3) ^ (srA1 & 3);
    const unsigned short* gA0 = A + (size_t)(m0 + srA) * K + scA0 * 8;
    const unsigned short* gA1 = A + (size_t)(m0 + srA1) * K + scA1 * 8;
    const unsigned short* gB0 = Bt + (size_t)(n0 + srA) * K + scA0 * 8;

    f32x4 acc[4][4] = {};

#define STAGE_A(buf, k0)                                                   \
    do {                                                                   \
        gload16(gA0 + (k0), As + (buf) * 8192 + w * 512);                  \
        gload16(gA1 + (k0), As + (buf) * 8192 + 4096 + w * 512);           \
    } while (0)
#define STAGE_B(buf, k0) gload16(gB0 + (k0), Bs + (buf) * 4096 + w * 512)

    STAGE_A(0, 0); STAGE_B(0, 0);
    STAGE_A(1, 32); STAGE_B(1, 32);
    asm volatile("s_waitcnt vmcnt(3)" ::: "memory");
    __builtin_amdgcn_s_barrier();
    __builtin_amdgcn_sched_barrier(0);

    int cur = 0;
    for (int kt = 0; kt < KT; ++kt) {
        int sb = cur + 2; if (sb >= 3) sb -= 3;
        bool pf = (kt + 2 < KT);
        const unsigned short* Ab = As + cur * 8192;
        const unsigned short* Bb = Bs + cur * 4096;

        short8 af0, af1, bf[4];
        {
            int r0 = wr * 64 + lr;
            int r1 = wr * 64 + 16 + lr;
            af0 = *reinterpret_cast<const short8*>(&Ab[r0 * 32 + (kc ^ (r0 & 3)) * 8]);
            af1 = *reinterpret_cast<const short8*>(&Ab[r1 * 32 + (kc ^ (r1 & 3)) * 8]);
            #pragma unroll
            for (int ni = 0; ni < 4; ni++) {
                int rb = wc * 64 + ni * 16 + lr;
                bf[ni] = *reinterpret_cast<const short8*>(&Bb[rb * 32 + (kc ^ (rb & 3)) * 8]);
            }
        }
        if (pf) STAGE_A(sb, (kt + 2) * 32);
        __builtin_amdgcn_s_barrier();
        asm volatile("s_waitcnt lgkmcnt(0)" ::: "memory");
        __builtin_amdgcn_sched_barrier(0);
        __builtin_amdgcn_s_setprio(1);
        #pragma unroll
        for (int ni = 0; ni < 4; ni++) {
            acc[0][ni] = __builtin_amdgcn_mfma_f32_16x16x32_bf16(af0, bf[ni], acc[0][ni], 0, 0, 0);
            acc[1][ni] = __builtin_amdgcn_mfma_f32_16x16x32_bf16(af1, bf[ni], acc[1][ni], 0, 0, 0);
        }
        __builtin_amdgcn_s_setprio(0);
        __builtin_amdgcn_s_barrier();
        __builtin_amdgcn_sched_barrier(0);

        short8 af2, af3;
        {
            int r2 = wr * 64 + 32 + lr;
            int r3 = wr * 64 + 48 + lr;
            af2 = *reinterpret_cast<const short8*>(&Ab[r2 * 32 + (kc ^ (r2 & 3)) * 8]);
            af3 = *reinterpret_cast<const short8*>(&Ab[r3 * 32 + (kc ^ (r3 & 3)) * 8]);
        }
        if (pf) STAGE_B(sb, (kt + 2) * 32);
        __builtin_amdgcn_s_barrier();
        asm volatile("s_waitcnt lgkmcnt(0)" ::: "memory");
        __builtin_amdgcn_sched_barrier(0);
        __builtin_amdgcn_s_setprio(1);
        #pragma unroll
        for (int ni = 0; ni < 4; ni++) {
            acc[2][ni] = __builtin_amdgcn_mfma_f32_16x16x32_bf16(af2, bf[ni], acc[2][ni], 0, 0, 0);
            acc[3][ni] = __builtin_amdgcn_mfma_f32_16x16x32_bf16(af3, bf[ni], acc[3][ni], 0, 0, 0);
        }
        __builtin_amdgcn_s_setprio(0);
        if (kt + 1 < KT) {
            if (pf) asm volatile("s_waitcnt vmcnt(3)" ::: "memory");
            else    asm volatile("s_waitcnt vmcnt(0)" ::: "memory");
        }
        __builtin_amdgcn_s_barrier();
        __builtin_amdgcn_sched_barrier(0);

        cur = (cur == 2) ? 0 : cur + 1;
    }
#undef STAGE_A
#undef STAGE_B

    if (n0 >= 1536) {
        #pragma unroll
        for (int mi = 0; mi < 4; mi++) {
            int nn0g = m0 + wr * 64 + mi * 16 + org;
            int b = nn0g >> 10, nn = nn0g & 1023;
            #pragma unroll
            for (int ni = 0; ni < 4; ni++) {
                int colg = n0 + wc * 64 + ni * 16 + lr;
                int rem = colg - 1536;
                int h = rem >> 6, dd = rem & 63;
                float bv = bias[colg];
                unsigned long long u = 0;
                #pragma unroll
                for (int r = 0; r < 4; r++)
                    u |= (unsigned long long)f2bf(acc[mi][ni][r] + bv) << (16 * r);
                *reinterpret_cast<unsigned long long*>(
                    vo + ((size_t)(b * H_ + h) * HD + dd) * N_ + nn) = u;
            }
        }
    } else {
        int which = n0 / 768;
        unsigned short* dst = (which == 0) ? qo : ko;
        float fold = (which == 0) ? 0.125f * 1.44269504088896f : 1.0f;
        #pragma unroll
        for (int mi = 0; mi < 4; mi++) {
            #pragma unroll
            for (int ni = 0; ni < 4; ni++) {
                int col = n0 + wc * 64 + ni * 16 + lr;
                int rem = col - which * 768;
                int h = rem >> 6, dd = rem & 63;
                float bv = bias[col];
                #pragma unroll
                for (int r = 0; r < 4; r++) {
                    int row = m0 + wr * 64 + mi * 16 + org + r;
                    int b = row >> 10, nn = row & 1023;
                    dst[(((size_t)(b * H_ + h) * N_ + nn) * HD) + dd] =
                        f2bf((acc[mi][ni][r] + bv) * fold);
                }
            }
        }
    }
}

// ---------------- gemm<1> (proj): 64x128 tile, 768 blocks = 3/CU (r19) ------

__global__ __launch_bounds__(256) void gemm1_kernel(
    const unsigned short* __restrict__ A,
    const unsigned short* __restrict__ Bt,
    const float* __restrict__ bias,
    float* __restrict__ outf,
    int Ndim, int K)
{
    __shared__ alignas(16) unsigned short As[3 * 2048];
    __shared__ alignas(16) unsigned short Bs[3 * 4096];

    int tid = threadIdx.x;
    int lane = tid & 63, w = tid >> 6;

    int nbx = Ndim >> 7;
    int nwg = gridDim.x;
    int cpx = nwg >> 3;
    int sbid = (blockIdx.x & 7) * cpx + (blockIdx.x >> 3);
    int bx = sbid % nbx, by = sbid / nbx;
    int m0 = by * 64, n0 = bx * 128;

    int lr = lane & 15, lk8 = (lane >> 4) * 8;
    int org = (lane >> 4) * 4;

    int srow = tid >> 2;
    int selem = (tid & 3) * 8;
    const unsigned short* gA = A + (size_t)(m0 + srow) * K + selem;
    const unsigned short* gB = Bt + (size_t)(n0 + srow) * K + selem;

    f32x4 acc[4][2] = {};

#define GSTAGE(buf, k0)                                                    \
    do {                                                                   \
        gload16(gA + (k0), As + (buf) * 2048 + w * 512);                   \
        gload16(gB + (k0), Bs + (buf) * 4096 + w * 512);                   \
        gload16(gB + (size_t)64 * K + (k0), Bs + (buf) * 4096 + 2048 + w * 512);\
    } while (0)

    GSTAGE(0, 0);
    GSTAGE(1, 32);
    asm volatile("s_waitcnt vmcnt(3)" ::: "memory");
    __builtin_amdgcn_s_barrier();
    __builtin_amdgcn_sched_barrier(0);

    int KT = K >> 5;
    int cur = 0;
    for (int kt = 0; kt < KT; ++kt) {
        int sb = cur + 2; if (sb >= 3) sb -= 3;
        if (kt + 2 < KT) GSTAGE(sb, (kt + 2) * 32);

        const unsigned short* Ab = As + cur * 2048;
        const unsigned short* Bb = Bs + cur * 4096;
        short8 af[4], bf[2];
        #pragma unroll
        for (int mi = 0; mi < 4; mi++)
            af[mi] = *reinterpret_cast<const short8*>(&Ab[(mi * 16 + lr) * 32 + lk8]);
        #pragma unroll
        for (int ni = 0; ni < 2; ni++)
            bf[ni] = *reinterpret_cast<const short8*>(&Bb[(w * 32 + ni * 16 + lr) * 32 + lk8]);
        asm volatile("s_waitcnt lgkmcnt(0)" ::: "memory");
        __builtin_amdgcn_sched_barrier(0);
        #pragma unroll
        for (int mi = 0; mi < 4; mi++)
            #pragma unroll
            for (int ni = 0; ni < 2; ni++)
                acc[mi][ni] = __builtin_amdgcn_mfma_f32_16x16x32_bf16(bf[ni], af[mi], acc[mi][ni], 0, 0, 0);

        if (kt + 1 < KT) {
            if (kt + 2 < KT)
                asm volatile("s_waitcnt vmcnt(3)" ::: "memory");
            else
                asm volatile("s_waitcnt vmcnt(0)" ::: "memory");
            __builtin_amdgcn_s_barrier();
            __builtin_amdgcn_sched_barrier(0);
            cur = (cur == 2) ? 0 : cur + 1;
        }
    }
#undef GSTAGE

    int m = m0 + lr;
    #pragma unroll
    for (int mi = 0; mi < 4; mi++) {
        int row = m + mi * 16;
        #pragma unroll
        for (int ni = 0; ni < 2; ni++) {
            int col = n0 + w * 32 + ni * 16 + org;
            float4 bv = *reinterpret_cast<const float4*>(&bias[col]);
            float4 o;
            o.x = acc[mi][ni][0] + bv.x;
            o.y = acc[mi][ni][1] + bv.y;
            o.z = acc[mi][ni][2] + bv.z;
            o.w = acc[mi][ni][3] + bv.w;
            *reinterpret_cast<float4*>(&outf[(size_t)row * Ndim + col]) = o;
        }
    }
}

// ---------------- Flash attention (r16/r18 config — unchanged) --------------

__global__ __launch_bounds__(256) void attn_kernel(
    const unsigned short* __restrict__ qg,
    const unsigned short* __restrict__ kg,
    const unsigned short* __restrict__ vtg,
    unsigned short* __restrict__ aout)
{
    __shared__ alignas(16) unsigned short Ks[3][4096];
    __shared__ alignas(16) unsigned short Vs[3][4096];

    int tid = threadIdx.x;
    int lane = tid & 63, w = tid >> 6;

    int bid = blockIdx.x;
    int xcd = bid & 7;
    int chunk = bid >> 3;
    int bh = xcd * 12 + (chunk % 12);
    int qblk = chunk / 12;
    int b = bh / H_, h = bh - b * H_;
    int q0w = qblk * 128 + w * 32;
    int l31 = lane & 31;
    int hi = lane >> 5;
    int swz = l31 & 7;

    const unsigned short* qp = qg + ((size_t)bh * N_ + q0w + l31) * HD + hi * 8;
    short8 qf[4];
    #pragma unroll
    for (int ds = 0; ds < 4; ds++)
        qf[ds] = *reinterpret_cast<const short8*>(qp + ds * 16);

    const unsigned short* kbh = kg + (size_t)bh * N_ * HD;
    const unsigned short* vtbh = vtg + (size_t)bh * HD * N_;

    int sr0 = tid >> 3;
    int sj0 = (tid & 7) ^ (sr0 & 7);
    int sr1 = sr0 + 32;
    int sj1 = (tid & 7) ^ (sr1 & 7);

    float m_run = -INFINITY, l_run = 0.f;
    f32x16 o0 = {}, o1 = {};

#define STAGE(buf, kv0)                                                        \
    do {                                                                       \
        gload16(kbh + (size_t)((kv0) + sr0) * HD + sj0 * 8, &Ks[buf][w * 512]);\
        gload16(kbh + (size_t)((kv0) + sr1) * HD + sj1 * 8, &Ks[buf][2048 + w * 512]);\
        gload16(vtbh + (size_t)sr0 * N_ + (kv0) + sj0 * 8, &Vs[buf][w * 512]); \
        gload16(vtbh + (size_t)sr1 * N_ + (kv0) + sj1 * 8, &Vs[buf][2048 + w * 512]);\
    } while (0)

    STAGE(0, 0);
    STAGE(1, 64);
    asm volatile("s_waitcnt vmcnt(4)" ::: "memory");
    __builtin_amdgcn_s_barrier();
    __builtin_amdgcn_sched_barrier(0);

    int cur = 0;
    for (int t = 0; t < 16; ++t) {
        int sb = cur + 2; if (sb >= 3) sb -= 3;
        bool pf = (t + 2 < 16);
        if (pf) STAGE(sb, (t + 2) * 64);

        const unsigned short* Ksb = Ks[cur];
        const unsigned short* Vsb = Vs[cur];

        f32x16 s0 = {}, s1 = {};
        __builtin_amdgcn_s_setprio(1);
        #pragma unroll
        for (int ds = 0; ds < 4; ds++) {
            int pc = (ds * 2 + hi) ^ swz;
            short8 kf0 = *reinterpret_cast<const short8*>(&Ksb[(l31) * 64 + pc * 8]);
            short8 kf1 = *reinterpret_cast<const short8*>(&Ksb[(32 + l31) * 64 + pc * 8]);
            s0 = __builtin_amdgcn_mfma_f32_32x32x16_bf16(kf0, qf[ds], s0, 0, 0, 0);
            s1 = __builtin_amdgcn_mfma_f32_32x32x16_bf16(kf1, qf[ds], s1, 0, 0, 0);
        }
        __builtin_amdgcn_s_setprio(0);

        float mx = s0[0];
        #pragma unroll
        for (int r = 1; r < 16; r++) mx = fmaxf(mx, s0[r]);
        #pragma unroll
        for (int r = 0; r < 16; r++) mx = fmaxf(mx, s1[r]);
        mx = fmaxf(mx, __shfl_xor(mx, 32, 64));

        if (__any(mx > m_run + 8.f)) {
            float mn = fmaxf(m_run, mx);
            float al = exp2_hw(m_run - mn);
            m_run = mn;
            l_run *= al;
            o0 *= al;
            o1 *= al;
        }

        float psum = 0.f;
        #pragma unroll
        for (int r = 0; r < 16; r++) { float p = exp2_hw(s0[r] - m_run); psum += p; s0[r] = p; }
        #pragma unroll
        for (int r = 0; r < 16; r++) { float p = exp2_hw(s1[r] - m_run); psum += p; s1[r] = p; }

        l_run += psum + __shfl_xor(psum, 32, 64);

        unsigned int c0[8], c1[8];
        #pragma unroll
        for (int i = 0; i < 8; i++) c0[i] = cvtpk_bf16(s0[2 * i], s0[2 * i + 1]);
        #pragma unroll
        for (int i = 0; i < 8; i++) c1[i] = cvtpk_bf16(s1[2 * i], s1[2 * i + 1]);
        PLSWAP(c0[0], c0[2]); PLSWAP(c0[1], c0[3]);
        PLSWAP(c0[4], c0[6]); PLSWAP(c0[5], c0[7]);
        PLSWAP(c1[0], c1[2]); PLSWAP(c1[1], c1[3]);
        PLSWAP(c1[4], c1[6]); PLSWAP(c1[5], c1[7]);
        short8 pa0 = pack4(c0[0], c0[1], c0[2], c0[3]);
        short8 pa1 = pack4(c0[4], c0[5], c0[6], c0[7]);
        short8 pa2 = pack4(c1[0], c1[1], c1[2], c1[3]);
        short8 pa3 = pack4(c1[4], c1[5], c1[6], c1[7]);

        __builtin_amdgcn_s_setprio(1);
        #pragma unroll
        for (int ks = 0; ks < 4; ks++) {
            int pc = (ks * 2 + hi) ^ swz;
            short8 vf0 = *reinterpret_cast<const short8*>(&Vsb[(l31) * 64 + pc * 8]);
            short8 vf1 = *reinterpret_cast<const short8*>(&Vsb[(32 + l31) * 64 + pc * 8]);
            short8 pa = (ks == 0) ? pa0 : (ks == 1) ? pa1 : (ks == 2) ? pa2 : pa3;
            o0 = __builtin_amdgcn_mfma_f32_32x32x16_bf16(vf0, pa, o0, 0, 0, 0);
            o1 = __builtin_amdgcn_mfma_f32_32x32x16_bf16(vf1, pa, o1, 0, 0, 0);
        }
        __builtin_amdgcn_s_setprio(0);

        if (t < 15) {
            if (pf) asm volatile("s_waitcnt vmcnt(4)" ::: "memory");
            else    asm volatile("s_waitcnt vmcnt(0)" ::: "memory");
            __builtin_amdgcn_s_barrier();
            __builtin_amdgcn_sched_barrier(0);
            cur = (cur == 2) ? 0 : cur + 1;
        }
    }
#undef STAGE

    float linv = 1.0f / l_run;
    unsigned short* op = aout + ((size_t)(b * N_ + q0w + l31)) * D_ + h * HD;
    #pragma unroll
    for (int rg = 0; rg < 4; rg++) {
        int dbase = 8 * rg + 4 * hi;
        unsigned long long u0 = 0, u1 = 0;
        #pragma unroll
        for (int k = 0; k < 4; k++) {
            u0 |= (unsigned long long)f2bf(o0[rg * 4 + k] * linv) << (16 * k);
            u1 |= (unsigned long long)f2bf(o1[rg * 4 + k] * linv) << (16 * k);
        }
        *reinterpret_cast<unsigned long long*>(op + dbase) = u0;
        *reinterpret_cast<unsigned long long*>(op + 32 + dbase) = u1;
    }
}

// ---------------- launch ----------------

extern "C" void kernel_launch(void* const* d_in, const int* in_sizes, int n_in,
                              void* d_out, int out_size, void* d_ws, size_t ws_size,
                              hipStream_t stream) {
    const float* x      = (const float*)d_in[0];
    const float* w_qkv  = (const float*)d_in[1];
    const float* b_qkv  = (const float*)d_in[2];
    const float* w_proj = (const float*)d_in[3];
    const float* b_proj = (const float*)d_in[4];
    float* out = (float*)d_out;

    char* ws = (char*)d_ws;
    unsigned short* xb     = (unsigned short*)(ws + 0);
    unsigned short* wqkvT  = (unsigned short*)(ws + 12582912);
    unsigned short* wprojT = (unsigned short*)(ws + 16121856);
    unsigned short* qb     = (unsigned short*)(ws + 17301504);
    unsigned short* kb     = (unsigned short*)(ws + 29884416);
    unsigned short* vtb    = (unsigned short*)(ws + 42467328);
    unsigned short* aout   = xb;

    prep_kernel<<<3648, 256, 0, stream>>>(x, w_qkv, w_proj, xb, wqkvT, wprojT);

    gemm0_kernel<<<dim3(18, 32), 512, 0, stream>>>(
        xb, wqkvT, b_qkv, qb, kb, vtb);

    attn_kernel<<<768, 256, 0, stream>>>(qb, kb, vtb, aout);

    gemm1_kernel<<<768, 256, 0, stream>>>(
        aout, wprojT, b_proj, out, D_, D_);
}